// Round 1
// baseline (846.092 us; speedup 1.0000x reference)
//
#include <hip/hip_runtime.h>
#include <math.h>

// GCN forward: 4x (matmul -> normalized gather over CSR -> bias+relu fused downstream)
// then global max-pool -> dot with Wr.

__global__ void init_kernel(float* deg, int* counts, int* cursor, float* pooled, int N) {
    int i = blockIdx.x * blockDim.x + threadIdx.x;
    if (i < N) { deg[i] = 1.0f; counts[i] = 0; cursor[i] = 0; }  // deg starts at 1.0 (self loop)
    if (i < 64) pooled[i] = 0.0f;                                 // relu>=0 so 0-bits is identity for max
}

__global__ void deg_count_kernel(const int* __restrict__ src, const int* __restrict__ dst,
                                 const float* __restrict__ w, float* deg, int* counts, int E) {
    int e = blockIdx.x * blockDim.x + threadIdx.x;
    if (e >= E) return;
    int d = dst[e];
    atomicAdd(&deg[d], w[e]);
    atomicAdd(&counts[d], 1);
}

__global__ void dinv_kernel(float* deg, int N) {
    int i = blockIdx.x * blockDim.x + threadIdx.x;
    if (i < N) { float d = deg[i]; deg[i] = d > 0.0f ? 1.0f / sqrtf(d) : 0.0f; }
}

// ---- two-level exclusive scan of counts -> rowptr ----
__global__ void scan1_kernel(const int* __restrict__ counts, int* bsums, int N) {
    __shared__ int s[256];
    int t = threadIdx.x, i = blockIdx.x * 256 + t;
    s[t] = (i < N) ? counts[i] : 0;
    __syncthreads();
    for (int o = 128; o > 0; o >>= 1) {
        if (t < o) s[t] += s[t + o];
        __syncthreads();
    }
    if (t == 0) bsums[blockIdx.x] = s[0];
}

__global__ void scan2_kernel(int* bsums, int nb) {  // nb <= 512
    __shared__ int s[512];
    int t = threadIdx.x;
    int v = (t < nb) ? bsums[t] : 0;
    s[t] = v; __syncthreads();
    for (int o = 1; o < 512; o <<= 1) {
        int x = (t >= o) ? s[t - o] : 0;
        __syncthreads();
        s[t] += x;
        __syncthreads();
    }
    if (t < nb) bsums[t] = s[t] - v;  // exclusive
}

__global__ void scan3_kernel(const int* __restrict__ counts, const int* __restrict__ bsums,
                             int* rowptr, int N) {
    __shared__ int s[256];
    int t = threadIdx.x, i = blockIdx.x * 256 + t;
    int v = (i < N) ? counts[i] : 0;
    s[t] = v; __syncthreads();
    for (int o = 1; o < 256; o <<= 1) {
        int x = (t >= o) ? s[t - o] : 0;
        __syncthreads();
        s[t] += x;
        __syncthreads();
    }
    if (i <= N) rowptr[i] = bsums[blockIdx.x] + s[t] - v;  // rowptr[N] == E
}

__global__ void fill_kernel(const int* __restrict__ src, const int* __restrict__ dst,
                            const float* __restrict__ w, const float* __restrict__ dinv,
                            const int* __restrict__ rowptr, int* cursor,
                            int* colsrc, float* normcsr, int E) {
    int e = blockIdx.x * blockDim.x + threadIdx.x;
    if (e >= E) return;
    int s = src[e], d = dst[e];
    int slot = atomicAdd(&cursor[d], 1);
    int p = rowptr[d] + slot;
    colsrc[p] = s;
    normcsr[p] = dinv[s] * w[e] * dinv[d];
}

// h = relu_maybe(xin + bprev) @ W ; wave per node, lane = out channel, W in LDS.
template<int K, bool FUSE>
__global__ void mm_kernel(const float* __restrict__ xin, const float* __restrict__ W,
                          const float* __restrict__ bprev, float* __restrict__ h, int N) {
    __shared__ float Wl[K * 64];
    for (int i = threadIdx.x; i < K * 64; i += blockDim.x) Wl[i] = W[i];
    __syncthreads();
    int wid = blockIdx.x * (blockDim.x >> 6) + (threadIdx.x >> 6);
    if (wid >= N) return;
    int lane = threadIdx.x & 63;
    float xv = 0.0f;
    if (K == 64) {
        xv = xin[wid * 64 + lane];
        if (FUSE) xv = fmaxf(xv + bprev[lane], 0.0f);
    } else {
        if (lane < K) xv = xin[wid * K + lane];
    }
    float acc = 0.0f;
#pragma unroll
    for (int k = 0; k < K; ++k)
        acc = fmaf(__shfl(xv, k), Wl[k * 64 + lane], acc);
    h[wid * 64 + lane] = acc;
}

// agg[d] = dinv[d]^2 * h[d] + sum_{incoming e} norm[e] * h[src[e]] ; wave per node.
__global__ void gather_kernel(const float* __restrict__ h, const int* __restrict__ rowptr,
                              const int* __restrict__ colsrc, const float* __restrict__ normcsr,
                              const float* __restrict__ dinv, float* __restrict__ agg, int N) {
    int wid = blockIdx.x * (blockDim.x >> 6) + (threadIdx.x >> 6);
    if (wid >= N) return;
    int lane = threadIdx.x & 63;
    float dn = dinv[wid];
    float acc = dn * dn * h[wid * 64 + lane];
    int jb = rowptr[wid], je = rowptr[wid + 1];
    for (int j = jb; j < je; ++j) {
        int s = colsrc[j];
        float nm = normcsr[j];
        acc = fmaf(nm, h[s * 64 + lane], acc);
    }
    agg[wid * 64 + lane] = acc;
}

// pooled[f] = max_n relu(agg[n][f] + b[f]) via per-lane running max + one uint atomicMax.
__global__ void pool_kernel(const float* __restrict__ agg, const float* __restrict__ b,
                            float* pooled, int N) {
    int lane = threadIdx.x & 63;
    int wid = blockIdx.x * (blockDim.x >> 6) + (threadIdx.x >> 6);
    int nw = gridDim.x * (blockDim.x >> 6);
    float bv = b[lane];
    float m = 0.0f;
    for (int n = wid; n < N; n += nw)
        m = fmaxf(m, agg[n * 64 + lane] + bv);
    atomicMax((unsigned int*)&pooled[lane], __float_as_uint(m));  // values >= 0
}

__global__ void out_kernel(const float* __restrict__ pooled, const float* __restrict__ Wr,
                           const float* __restrict__ br, float* out) {
    int lane = threadIdx.x;
    float v = pooled[lane] * Wr[lane];
    for (int o = 32; o > 0; o >>= 1) v += __shfl_xor(v, o);
    if (lane == 0) out[0] = v + br[0];
}

extern "C" void kernel_launch(void* const* d_in, const int* in_sizes, int n_in,
                              void* d_out, int out_size, void* d_ws, size_t ws_size,
                              hipStream_t stream) {
    const float* vf = (const float*)d_in[0];
    const int* edges = (const int*)d_in[1];
    const float* w = (const float*)d_in[2];
    const float* W1 = (const float*)d_in[3];  const float* b1 = (const float*)d_in[4];
    const float* W2 = (const float*)d_in[5];  const float* b2 = (const float*)d_in[6];
    const float* W3 = (const float*)d_in[7];  const float* b3 = (const float*)d_in[8];
    const float* W4 = (const float*)d_in[9];  const float* b4 = (const float*)d_in[10];
    const float* Wr = (const float*)d_in[11]; const float* br = (const float*)d_in[12];
    float* out = (float*)d_out;

    const int FIN = 6;
    const int N = in_sizes[0] / FIN;   // 100000
    const int E = in_sizes[2];         // 800000
    const int* src = edges;
    const int* dst = edges + E;

    char* p = (char*)d_ws;
    float* dinv    = (float*)p;  p += (size_t)N * 4;
    int*   rowptr  = (int*)p;    p += (size_t)(N + 1) * 4;
    int*   counts  = (int*)p;    p += (size_t)N * 4;
    int*   cursor  = (int*)p;    p += (size_t)N * 4;
    int*   colsrc  = (int*)p;    p += (size_t)E * 4;
    float* normcsr = (float*)p;  p += (size_t)E * 4;
    float* h       = (float*)p;  p += (size_t)N * 64 * 4;
    float* agg     = (float*)p;  p += (size_t)N * 64 * 4;
    float* pooled  = (float*)p;  p += 64 * 4;
    int*   bsums   = (int*)p;    p += 512 * 4;

    const int nbN = (N + 255) / 256;   // 391
    const int nbE = (E + 255) / 256;   // 3125
    const int nbW = (N + 3) / 4;       // wave-per-node, 4 waves/block

    init_kernel<<<nbN, 256, 0, stream>>>(dinv, counts, cursor, pooled, N);
    deg_count_kernel<<<nbE, 256, 0, stream>>>(src, dst, w, dinv, counts, E);
    dinv_kernel<<<nbN, 256, 0, stream>>>(dinv, N);
    scan1_kernel<<<nbN, 256, 0, stream>>>(counts, bsums, N);
    scan2_kernel<<<1, 512, 0, stream>>>(bsums, nbN);
    scan3_kernel<<<nbN, 256, 0, stream>>>(counts, bsums, rowptr, N);
    fill_kernel<<<nbE, 256, 0, stream>>>(src, dst, w, dinv, rowptr, cursor, colsrc, normcsr, E);

    mm_kernel<6, false><<<nbW, 256, 0, stream>>>(vf, W1, nullptr, h, N);
    gather_kernel<<<nbW, 256, 0, stream>>>(h, rowptr, colsrc, normcsr, dinv, agg, N);
    mm_kernel<64, true><<<nbW, 256, 0, stream>>>(agg, W2, b1, h, N);
    gather_kernel<<<nbW, 256, 0, stream>>>(h, rowptr, colsrc, normcsr, dinv, agg, N);
    mm_kernel<64, true><<<nbW, 256, 0, stream>>>(agg, W3, b2, h, N);
    gather_kernel<<<nbW, 256, 0, stream>>>(h, rowptr, colsrc, normcsr, dinv, agg, N);
    mm_kernel<64, true><<<nbW, 256, 0, stream>>>(agg, W4, b3, h, N);
    gather_kernel<<<nbW, 256, 0, stream>>>(h, rowptr, colsrc, normcsr, dinv, agg, N);

    pool_kernel<<<256, 256, 0, stream>>>(agg, b4, pooled, N);
    out_kernel<<<1, 64, 0, stream>>>(pooled, Wr, br, out);
}

// Round 2
// 508.917 us; speedup vs baseline: 1.6625x; 1.6625x over previous
//
#include <hip/hip_runtime.h>
#include <math.h>

// GCN forward, reordered per-layer as x_{l} = relu((A x_{l-1}) @ W_l + b_l)
// (valid since A(xW) == (Ax)W). Then global max pool -> dot Wr.

__global__ void init_kernel(float* deg, int* counts, int* cursor, float* pooled, int N) {
    int i = blockIdx.x * blockDim.x + threadIdx.x;
    if (i < N) { deg[i] = 1.0f; counts[i] = 0; cursor[i] = 0; }  // deg starts at 1.0 (self loop)
    if (i < 64) pooled[i] = 0.0f;                                 // relu>=0 so 0-bits is max identity
}

__global__ void deg_count_kernel(const int* __restrict__ src, const int* __restrict__ dst,
                                 const float* __restrict__ w, float* deg, int* counts, int E) {
    int e = blockIdx.x * blockDim.x + threadIdx.x;
    if (e >= E) return;
    int d = dst[e];
    atomicAdd(&deg[d], w[e]);
    atomicAdd(&counts[d], 1);
}

__global__ void dinv_kernel(float* deg, int N) {
    int i = blockIdx.x * blockDim.x + threadIdx.x;
    if (i < N) { float d = deg[i]; deg[i] = d > 0.0f ? 1.0f / sqrtf(d) : 0.0f; }
}

// ---- two-level exclusive scan of counts -> rowptr ----
__global__ void scan1_kernel(const int* __restrict__ counts, int* bsums, int N) {
    __shared__ int s[256];
    int t = threadIdx.x, i = blockIdx.x * 256 + t;
    s[t] = (i < N) ? counts[i] : 0;
    __syncthreads();
    for (int o = 128; o > 0; o >>= 1) {
        if (t < o) s[t] += s[t + o];
        __syncthreads();
    }
    if (t == 0) bsums[blockIdx.x] = s[0];
}

__global__ void scan2_kernel(int* bsums, int nb) {  // nb <= 512
    __shared__ int s[512];
    int t = threadIdx.x;
    int v = (t < nb) ? bsums[t] : 0;
    s[t] = v; __syncthreads();
    for (int o = 1; o < 512; o <<= 1) {
        int x = (t >= o) ? s[t - o] : 0;
        __syncthreads();
        s[t] += x;
        __syncthreads();
    }
    if (t < nb) bsums[t] = s[t] - v;  // exclusive
}

__global__ void scan3_kernel(const int* __restrict__ counts, const int* __restrict__ bsums,
                             int* rowptr, int N) {
    __shared__ int s[256];
    int t = threadIdx.x, i = blockIdx.x * 256 + t;
    int v = (i < N) ? counts[i] : 0;
    s[t] = v; __syncthreads();
    for (int o = 1; o < 256; o <<= 1) {
        int x = (t >= o) ? s[t - o] : 0;
        __syncthreads();
        s[t] += x;
        __syncthreads();
    }
    if (i <= N) rowptr[i] = bsums[blockIdx.x] + s[t] - v;  // rowptr[N] == E
}

__global__ void fill_kernel(const int* __restrict__ src, const int* __restrict__ dst,
                            const float* __restrict__ w, const float* __restrict__ dinv,
                            const int* __restrict__ rowptr, int* cursor,
                            int* colsrc, float* normcsr, int E) {
    int e = blockIdx.x * blockDim.x + threadIdx.x;
    if (e >= E) return;
    int s = src[e], d = dst[e];
    int slot = atomicAdd(&cursor[d], 1);
    int p = rowptr[d] + slot;
    colsrc[p] = s;
    normcsr[p] = dinv[s] * w[e] * dinv[d];
}

// 6-wide gather over raw input features: g[i] = dinv[i]^2*x[i] + sum norm*x[src].
// Thread per node; x is 2.4MB -> L2 resident.
__global__ void gather6_kernel(const float* __restrict__ x, const int* __restrict__ rowptr,
                               const int* __restrict__ colsrc, const float* __restrict__ normcsr,
                               const float* __restrict__ dinv, float* __restrict__ g, int N) {
    int i = blockIdx.x * blockDim.x + threadIdx.x;
    if (i >= N) return;
    float dn = dinv[i];
    float sc = dn * dn;
    float acc[6];
#pragma unroll
    for (int f = 0; f < 6; ++f) acc[f] = sc * x[(size_t)i * 6 + f];
    int jb = rowptr[i], je = rowptr[i + 1];
    for (int j = jb; j < je; ++j) {
        int s = colsrc[j];
        float nm = normcsr[j];
#pragma unroll
        for (int f = 0; f < 6; ++f) acc[f] = fmaf(nm, x[(size_t)s * 6 + f], acc[f]);
    }
#pragma unroll
    for (int f = 0; f < 6; ++f) g[(size_t)i * 6 + f] = acc[f];
}

// 64-wide gather: wave per node, 4 edge-groups x 16 lanes, float4 per lane.
// 4 source rows in flight per iteration; cross-group shfl reduce at the end.
__global__ void gather64_kernel(const float* __restrict__ h, const int* __restrict__ rowptr,
                                const int* __restrict__ colsrc, const float* __restrict__ normcsr,
                                const float* __restrict__ dinv, float* __restrict__ agg, int N) {
    int wid = blockIdx.x * (blockDim.x >> 6) + (threadIdx.x >> 6);
    if (wid >= N) return;
    int lane = threadIdx.x & 63;
    int g = lane >> 4;       // edge group 0..3
    int l16 = lane & 15;     // float4 slot within row
    float4 acc = {0.f, 0.f, 0.f, 0.f};
    if (g == 0) {
        float dn = dinv[wid];
        float sc = dn * dn;
        float4 v = ((const float4*)(h + (size_t)wid * 64))[l16];
        acc.x = sc * v.x; acc.y = sc * v.y; acc.z = sc * v.z; acc.w = sc * v.w;
    }
    int jb = rowptr[wid], je = rowptr[wid + 1];
    for (int j = jb + g; j < je; j += 4) {
        int s = colsrc[j];
        float nm = normcsr[j];
        float4 v = ((const float4*)(h + (size_t)s * 64))[l16];
        acc.x = fmaf(nm, v.x, acc.x);
        acc.y = fmaf(nm, v.y, acc.y);
        acc.z = fmaf(nm, v.z, acc.z);
        acc.w = fmaf(nm, v.w, acc.w);
    }
#pragma unroll
    for (int o = 16; o <= 32; o <<= 1) {
        acc.x += __shfl_xor(acc.x, o);
        acc.y += __shfl_xor(acc.y, o);
        acc.z += __shfl_xor(acc.z, o);
        acc.w += __shfl_xor(acc.w, o);
    }
    if (g == 0) ((float4*)(agg + (size_t)wid * 64))[l16] = acc;
}

// h[i] = relu(g[i] @ W + b). Thread per node; acc[64] in VGPRs; W/b are
// uniform loads -> SGPR operands, inner loop is pure v_fmac_f32.
template<int K>
__global__ void mm_kernel(const float* __restrict__ xin, const float* __restrict__ W,
                          const float* __restrict__ b, float* __restrict__ h, int N) {
    int i = blockIdx.x * blockDim.x + threadIdx.x;
    if (i >= N) return;
    float acc[64];
#pragma unroll
    for (int j = 0; j < 64; ++j) acc[j] = 0.0f;

    if (K == 64) {
        const float4* xr = (const float4*)(xin + (size_t)i * 64);
#pragma unroll
        for (int k4 = 0; k4 < 16; ++k4) {
            float4 xv = xr[k4];
            float xs[4] = {xv.x, xv.y, xv.z, xv.w};
#pragma unroll
            for (int kk = 0; kk < 4; ++kk) {
                float x = xs[kk];
                int k = k4 * 4 + kk;
#pragma unroll
                for (int j = 0; j < 64; ++j)
                    acc[j] = fmaf(x, W[k * 64 + j], acc[j]);
            }
        }
    } else {
        const float2* xr = (const float2*)(xin + (size_t)i * K);  // K=6: 24B, 8B aligned
        float xs[K];
#pragma unroll
        for (int k2 = 0; k2 < K / 2; ++k2) {
            float2 v = xr[k2];
            xs[k2 * 2] = v.x; xs[k2 * 2 + 1] = v.y;
        }
#pragma unroll
        for (int k = 0; k < K; ++k) {
            float x = xs[k];
#pragma unroll
            for (int j = 0; j < 64; ++j)
                acc[j] = fmaf(x, W[k * 64 + j], acc[j]);
        }
    }

    float4* out = (float4*)(h + (size_t)i * 64);
#pragma unroll
    for (int j4 = 0; j4 < 16; ++j4) {
        float4 o;
        o.x = fmaxf(acc[j4 * 4 + 0] + b[j4 * 4 + 0], 0.0f);
        o.y = fmaxf(acc[j4 * 4 + 1] + b[j4 * 4 + 1], 0.0f);
        o.z = fmaxf(acc[j4 * 4 + 2] + b[j4 * 4 + 2], 0.0f);
        o.w = fmaxf(acc[j4 * 4 + 3] + b[j4 * 4 + 3], 0.0f);
        out[j4] = o;
    }
}

// pooled[f] = max_n x4[n][f] via per-lane running max + one uint atomicMax (values >= 0).
__global__ void pool_kernel(const float* __restrict__ x, float* pooled, int N) {
    int lane = threadIdx.x & 63;
    int wid = blockIdx.x * (blockDim.x >> 6) + (threadIdx.x >> 6);
    int nw = gridDim.x * (blockDim.x >> 6);
    float m = 0.0f;
    for (int n = wid; n < N; n += nw)
        m = fmaxf(m, x[(size_t)n * 64 + lane]);
    atomicMax((unsigned int*)&pooled[lane], __float_as_uint(m));
}

__global__ void out_kernel(const float* __restrict__ pooled, const float* __restrict__ Wr,
                           const float* __restrict__ br, float* out) {
    int lane = threadIdx.x;
    float v = pooled[lane] * Wr[lane];
    for (int o = 32; o > 0; o >>= 1) v += __shfl_xor(v, o);
    if (lane == 0) out[0] = v + br[0];
}

extern "C" void kernel_launch(void* const* d_in, const int* in_sizes, int n_in,
                              void* d_out, int out_size, void* d_ws, size_t ws_size,
                              hipStream_t stream) {
    const float* vf = (const float*)d_in[0];
    const int* edges = (const int*)d_in[1];
    const float* w = (const float*)d_in[2];
    const float* W1 = (const float*)d_in[3];  const float* b1 = (const float*)d_in[4];
    const float* W2 = (const float*)d_in[5];  const float* b2 = (const float*)d_in[6];
    const float* W3 = (const float*)d_in[7];  const float* b3 = (const float*)d_in[8];
    const float* W4 = (const float*)d_in[9];  const float* b4 = (const float*)d_in[10];
    const float* Wr = (const float*)d_in[11]; const float* br = (const float*)d_in[12];
    float* out = (float*)d_out;

    const int FIN = 6;
    const int N = in_sizes[0] / FIN;   // 100000
    const int E = in_sizes[2];         // 800000
    const int* src = edges;
    const int* dst = edges + E;

    char* p = (char*)d_ws;
    float* dinv    = (float*)p;  p += (size_t)N * 4;
    int*   rowptr  = (int*)p;    p += (size_t)(N + 1) * 4;
    int*   counts  = (int*)p;    p += (size_t)N * 4;
    int*   cursor  = (int*)p;    p += (size_t)N * 4;
    int*   colsrc  = (int*)p;    p += (size_t)E * 4;
    float* normcsr = (float*)p;  p += (size_t)E * 4;
    float* g6      = (float*)p;  p += (size_t)N * 6 * 4;
    float* h       = (float*)p;  p += (size_t)N * 64 * 4;
    float* agg     = (float*)p;  p += (size_t)N * 64 * 4;
    float* pooled  = (float*)p;  p += 64 * 4;
    int*   bsums   = (int*)p;    p += 512 * 4;

    const int nbN = (N + 255) / 256;   // 391
    const int nbE = (E + 255) / 256;   // 3125
    const int nbW = (N + 3) / 4;       // wave-per-node, 4 waves/block

    init_kernel<<<nbN, 256, 0, stream>>>(dinv, counts, cursor, pooled, N);
    deg_count_kernel<<<nbE, 256, 0, stream>>>(src, dst, w, dinv, counts, E);
    dinv_kernel<<<nbN, 256, 0, stream>>>(dinv, N);
    scan1_kernel<<<nbN, 256, 0, stream>>>(counts, bsums, N);
    scan2_kernel<<<1, 512, 0, stream>>>(bsums, nbN);
    scan3_kernel<<<nbN, 256, 0, stream>>>(counts, bsums, rowptr, N);
    fill_kernel<<<nbE, 256, 0, stream>>>(src, dst, w, dinv, rowptr, cursor, colsrc, normcsr, E);

    // layer 1: gather 6-wide, then mm 6->64 (+bias+relu)
    gather6_kernel<<<nbN, 256, 0, stream>>>(vf, rowptr, colsrc, normcsr, dinv, g6, N);
    mm_kernel<6><<<nbN, 256, 0, stream>>>(g6, W1, b1, h, N);
    // layers 2-4: gather 64-wide, then mm 64->64 (+bias+relu)
    gather64_kernel<<<nbW, 256, 0, stream>>>(h, rowptr, colsrc, normcsr, dinv, agg, N);
    mm_kernel<64><<<nbN, 256, 0, stream>>>(agg, W2, b2, h, N);
    gather64_kernel<<<nbW, 256, 0, stream>>>(h, rowptr, colsrc, normcsr, dinv, agg, N);
    mm_kernel<64><<<nbN, 256, 0, stream>>>(agg, W3, b3, h, N);
    gather64_kernel<<<nbW, 256, 0, stream>>>(h, rowptr, colsrc, normcsr, dinv, agg, N);
    mm_kernel<64><<<nbN, 256, 0, stream>>>(agg, W4, b4, h, N);

    pool_kernel<<<256, 256, 0, stream>>>(h, pooled, N);
    out_kernel<<<1, 64, 0, stream>>>(pooled, Wr, br, out);
}

// Round 3
// 463.797 us; speedup vs baseline: 1.8243x; 1.0973x over previous
//
#include <hip/hip_runtime.h>
#include <math.h>

// GCN forward, reordered per-layer as x_{l} = relu((A x_{l-1}) @ W_l + b_l)
// (valid since A(xW) == (Ax)W). Then global max pool -> dot Wr.
//
// CSR build: one atomic pass (slot reservation) + scan + atomic-free fill;
// degree = coalesced row-sum of CSR weights (self-loop handled analytically).

__global__ void init_kernel(int* counts, float* pooled, int N) {
    int i = blockIdx.x * blockDim.x + threadIdx.x;
    if (i < N) counts[i] = 0;
    if (i < 64) pooled[i] = 0.0f;  // relu >= 0 so 0-bits is max identity
}

// pass 1: reserve a slot per edge within its dst row. 800k atomics total.
__global__ void count_slot_kernel(const int* __restrict__ dst, int* counts, int* eslot, int E) {
    int e = blockIdx.x * blockDim.x + threadIdx.x;
    if (e >= E) return;
    eslot[e] = atomicAdd(&counts[dst[e]], 1);
}

// ---- two-level exclusive scan of counts -> rowptr ----
__global__ void scan1_kernel(const int* __restrict__ counts, int* bsums, int N) {
    __shared__ int s[256];
    int t = threadIdx.x, i = blockIdx.x * 256 + t;
    s[t] = (i < N) ? counts[i] : 0;
    __syncthreads();
    for (int o = 128; o > 0; o >>= 1) {
        if (t < o) s[t] += s[t + o];
        __syncthreads();
    }
    if (t == 0) bsums[blockIdx.x] = s[0];
}

__global__ void scan2_kernel(int* bsums, int nb) {  // nb <= 512
    __shared__ int s[512];
    int t = threadIdx.x;
    int v = (t < nb) ? bsums[t] : 0;
    s[t] = v; __syncthreads();
    for (int o = 1; o < 512; o <<= 1) {
        int x = (t >= o) ? s[t - o] : 0;
        __syncthreads();
        s[t] += x;
        __syncthreads();
    }
    if (t < nb) bsums[t] = s[t] - v;  // exclusive
}

__global__ void scan3_kernel(const int* __restrict__ counts, const int* __restrict__ bsums,
                             int* rowptr, int N) {
    __shared__ int s[256];
    int t = threadIdx.x, i = blockIdx.x * 256 + t;
    int v = (i < N) ? counts[i] : 0;
    s[t] = v; __syncthreads();
    for (int o = 1; o < 256; o <<= 1) {
        int x = (t >= o) ? s[t - o] : 0;
        __syncthreads();
        s[t] += x;
        __syncthreads();
    }
    if (i <= N) rowptr[i] = bsums[blockIdx.x] + s[t] - v;  // rowptr[N] == E
}

// pass 2: atomic-free CSR fill using reserved slots.
__global__ void fill2_kernel(const int* __restrict__ src, const int* __restrict__ dst,
                             const float* __restrict__ w, const int* __restrict__ rowptr,
                             const int* __restrict__ eslot, int* colsrc, float* wcsr, int E) {
    int e = blockIdx.x * blockDim.x + threadIdx.x;
    if (e >= E) return;
    int p = rowptr[dst[e]] + eslot[e];
    colsrc[p] = src[e];
    wcsr[p] = w[e];
}

// deg[i] = 1 + sum(wcsr row) (self loop), dinv = 1/sqrt(deg). Coalesced, no atomics.
__global__ void degdinv_kernel(const float* __restrict__ wcsr, const int* __restrict__ rowptr,
                               float* dinv, int N) {
    int i = blockIdx.x * blockDim.x + threadIdx.x;
    if (i >= N) return;
    float d = 1.0f;
    int jb = rowptr[i], je = rowptr[i + 1];
    for (int j = jb; j < je; ++j) d += wcsr[j];
    dinv[i] = 1.0f / sqrtf(d);
}

// in-place: wcsr[j] <- dinv[colsrc[j]] * wcsr[j] * dinv[i]
__global__ void norm_kernel(const int* __restrict__ rowptr, const int* __restrict__ colsrc,
                            const float* __restrict__ dinv, float* wcsr, int N) {
    int i = blockIdx.x * blockDim.x + threadIdx.x;
    if (i >= N) return;
    float dn = dinv[i];
    int jb = rowptr[i], je = rowptr[i + 1];
    for (int j = jb; j < je; ++j)
        wcsr[j] = dinv[colsrc[j]] * wcsr[j] * dn;
}

// 6-wide gather over raw input features: g[i] = dinv[i]^2*x[i] + sum norm*x[src].
__global__ void gather6_kernel(const float* __restrict__ x, const int* __restrict__ rowptr,
                               const int* __restrict__ colsrc, const float* __restrict__ normcsr,
                               const float* __restrict__ dinv, float* __restrict__ g, int N) {
    int i = blockIdx.x * blockDim.x + threadIdx.x;
    if (i >= N) return;
    float dn = dinv[i];
    float sc = dn * dn;
    float acc[6];
    {
        const float2* xr = (const float2*)(x + (size_t)i * 6);
        float2 a = xr[0], bv = xr[1], c = xr[2];
        acc[0] = sc * a.x; acc[1] = sc * a.y; acc[2] = sc * bv.x;
        acc[3] = sc * bv.y; acc[4] = sc * c.x; acc[5] = sc * c.y;
    }
    int jb = rowptr[i], je = rowptr[i + 1];
    for (int j = jb; j < je; ++j) {
        int s = colsrc[j];
        float nm = normcsr[j];
        const float2* xr = (const float2*)(x + (size_t)s * 6);
        float2 a = xr[0], bv = xr[1], c = xr[2];
        acc[0] = fmaf(nm, a.x, acc[0]); acc[1] = fmaf(nm, a.y, acc[1]);
        acc[2] = fmaf(nm, bv.x, acc[2]); acc[3] = fmaf(nm, bv.y, acc[3]);
        acc[4] = fmaf(nm, c.x, acc[4]); acc[5] = fmaf(nm, c.y, acc[5]);
    }
#pragma unroll
    for (int f = 0; f < 6; ++f) g[(size_t)i * 6 + f] = acc[f];
}

// 64-wide gather: wave per node, 4 edge-groups x 16 lanes, float4 per lane.
__global__ void gather64_kernel(const float* __restrict__ h, const int* __restrict__ rowptr,
                                const int* __restrict__ colsrc, const float* __restrict__ normcsr,
                                const float* __restrict__ dinv, float* __restrict__ agg, int N) {
    int wid = blockIdx.x * (blockDim.x >> 6) + (threadIdx.x >> 6);
    if (wid >= N) return;
    int lane = threadIdx.x & 63;
    int g = lane >> 4;       // edge group 0..3
    int l16 = lane & 15;     // float4 slot within row
    float4 acc = {0.f, 0.f, 0.f, 0.f};
    if (g == 0) {
        float dn = dinv[wid];
        float sc = dn * dn;
        float4 v = ((const float4*)(h + (size_t)wid * 64))[l16];
        acc.x = sc * v.x; acc.y = sc * v.y; acc.z = sc * v.z; acc.w = sc * v.w;
    }
    int jb = rowptr[wid], je = rowptr[wid + 1];
    for (int j = jb + g; j < je; j += 4) {
        int s = colsrc[j];
        float nm = normcsr[j];
        float4 v = ((const float4*)(h + (size_t)s * 64))[l16];
        acc.x = fmaf(nm, v.x, acc.x);
        acc.y = fmaf(nm, v.y, acc.y);
        acc.z = fmaf(nm, v.z, acc.z);
        acc.w = fmaf(nm, v.w, acc.w);
    }
#pragma unroll
    for (int o = 16; o <= 32; o <<= 1) {
        acc.x += __shfl_xor(acc.x, o);
        acc.y += __shfl_xor(acc.y, o);
        acc.z += __shfl_xor(acc.z, o);
        acc.w += __shfl_xor(acc.w, o);
    }
    if (g == 0) ((float4*)(agg + (size_t)wid * 64))[l16] = acc;
}

// h[i] = relu(g[i] @ W + b). Thread per node; acc[64] in VGPRs (launch_bounds
// opens the VGPR budget so it does NOT spill); W/b scalarize to s_load.
template<int K>
__global__ void __launch_bounds__(256, 1)
mm_kernel(const float* __restrict__ xin, const float* __restrict__ W,
          const float* __restrict__ b, float* __restrict__ h, int N) {
    int i = blockIdx.x * blockDim.x + threadIdx.x;
    if (i >= N) return;
    float acc[64];
#pragma unroll
    for (int j = 0; j < 64; ++j) acc[j] = 0.0f;

    if (K == 64) {
        const float4* xr = (const float4*)(xin + (size_t)i * 64);
#pragma unroll
        for (int k4 = 0; k4 < 16; ++k4) {
            float4 xv = xr[k4];
            float xs[4] = {xv.x, xv.y, xv.z, xv.w};
#pragma unroll
            for (int kk = 0; kk < 4; ++kk) {
                float x = xs[kk];
                int k = k4 * 4 + kk;
#pragma unroll
                for (int j = 0; j < 64; ++j)
                    acc[j] = fmaf(x, W[k * 64 + j], acc[j]);
            }
        }
    } else {
        const float2* xr = (const float2*)(xin + (size_t)i * K);  // K=6: 24B, 8B aligned
        float xs[K];
#pragma unroll
        for (int k2 = 0; k2 < K / 2; ++k2) {
            float2 v = xr[k2];
            xs[k2 * 2] = v.x; xs[k2 * 2 + 1] = v.y;
        }
#pragma unroll
        for (int k = 0; k < K; ++k) {
            float x = xs[k];
#pragma unroll
            for (int j = 0; j < 64; ++j)
                acc[j] = fmaf(x, W[k * 64 + j], acc[j]);
        }
    }

    float4* out = (float4*)(h + (size_t)i * 64);
#pragma unroll
    for (int j4 = 0; j4 < 16; ++j4) {
        float4 o;
        o.x = fmaxf(acc[j4 * 4 + 0] + b[j4 * 4 + 0], 0.0f);
        o.y = fmaxf(acc[j4 * 4 + 1] + b[j4 * 4 + 1], 0.0f);
        o.z = fmaxf(acc[j4 * 4 + 2] + b[j4 * 4 + 2], 0.0f);
        o.w = fmaxf(acc[j4 * 4 + 3] + b[j4 * 4 + 3], 0.0f);
        out[j4] = o;
    }
}

// pooled[f] = max_n x[n][f] via per-lane running max + one uint atomicMax (values >= 0).
__global__ void pool_kernel(const float* __restrict__ x, float* pooled, int N) {
    int lane = threadIdx.x & 63;
    int wid = blockIdx.x * (blockDim.x >> 6) + (threadIdx.x >> 6);
    int nw = gridDim.x * (blockDim.x >> 6);
    float m = 0.0f;
    for (int n = wid; n < N; n += nw)
        m = fmaxf(m, x[(size_t)n * 64 + lane]);
    atomicMax((unsigned int*)&pooled[lane], __float_as_uint(m));
}

__global__ void out_kernel(const float* __restrict__ pooled, const float* __restrict__ Wr,
                           const float* __restrict__ br, float* out) {
    int lane = threadIdx.x;
    float v = pooled[lane] * Wr[lane];
    for (int o = 32; o > 0; o >>= 1) v += __shfl_xor(v, o);
    if (lane == 0) out[0] = v + br[0];
}

extern "C" void kernel_launch(void* const* d_in, const int* in_sizes, int n_in,
                              void* d_out, int out_size, void* d_ws, size_t ws_size,
                              hipStream_t stream) {
    const float* vf = (const float*)d_in[0];
    const int* edges = (const int*)d_in[1];
    const float* w = (const float*)d_in[2];
    const float* W1 = (const float*)d_in[3];  const float* b1 = (const float*)d_in[4];
    const float* W2 = (const float*)d_in[5];  const float* b2 = (const float*)d_in[6];
    const float* W3 = (const float*)d_in[7];  const float* b3 = (const float*)d_in[8];
    const float* W4 = (const float*)d_in[9];  const float* b4 = (const float*)d_in[10];
    const float* Wr = (const float*)d_in[11]; const float* br = (const float*)d_in[12];
    float* out = (float*)d_out;

    const int FIN = 6;
    const int N = in_sizes[0] / FIN;   // 100000
    const int E = in_sizes[2];         // 800000
    const int* src = edges;
    const int* dst = edges + E;

    char* p = (char*)d_ws;
    float* dinv    = (float*)p;  p += (size_t)N * 4;
    int*   rowptr  = (int*)p;    p += (size_t)(N + 1) * 4;
    int*   counts  = (int*)p;    p += (size_t)N * 4;
    int*   eslot   = (int*)p;    p += (size_t)E * 4;
    int*   colsrc  = (int*)p;    p += (size_t)E * 4;
    float* wcsr    = (float*)p;  p += (size_t)E * 4;   // becomes normcsr in-place
    float* g6      = (float*)p;  p += (size_t)N * 6 * 4;
    float* h       = (float*)p;  p += (size_t)N * 64 * 4;
    float* agg     = (float*)p;  p += (size_t)N * 64 * 4;
    float* pooled  = (float*)p;  p += 64 * 4;
    int*   bsums   = (int*)p;    p += 512 * 4;

    const int nbN = (N + 255) / 256;   // 391
    const int nbE = (E + 255) / 256;   // 3125
    const int nbW = (N + 3) / 4;       // wave-per-node, 4 waves/block

    init_kernel<<<nbN, 256, 0, stream>>>(counts, pooled, N);
    count_slot_kernel<<<nbE, 256, 0, stream>>>(dst, counts, eslot, E);
    scan1_kernel<<<nbN, 256, 0, stream>>>(counts, bsums, N);
    scan2_kernel<<<1, 512, 0, stream>>>(bsums, nbN);
    scan3_kernel<<<nbN, 256, 0, stream>>>(counts, bsums, rowptr, N);
    fill2_kernel<<<nbE, 256, 0, stream>>>(src, dst, w, rowptr, eslot, colsrc, wcsr, E);
    degdinv_kernel<<<nbN, 256, 0, stream>>>(wcsr, rowptr, dinv, N);
    norm_kernel<<<nbN, 256, 0, stream>>>(rowptr, colsrc, dinv, wcsr, N);

    // layer 1: gather 6-wide, then mm 6->64 (+bias+relu)
    gather6_kernel<<<nbN, 256, 0, stream>>>(vf, rowptr, colsrc, wcsr, dinv, g6, N);
    mm_kernel<6><<<nbN, 256, 0, stream>>>(g6, W1, b1, h, N);
    // layers 2-4: gather 64-wide, then mm 64->64 (+bias+relu)
    gather64_kernel<<<nbW, 256, 0, stream>>>(h, rowptr, colsrc, wcsr, dinv, agg, N);
    mm_kernel<64><<<nbN, 256, 0, stream>>>(agg, W2, b2, h, N);
    gather64_kernel<<<nbW, 256, 0, stream>>>(h, rowptr, colsrc, wcsr, dinv, agg, N);
    mm_kernel<64><<<nbN, 256, 0, stream>>>(agg, W3, b3, h, N);
    gather64_kernel<<<nbW, 256, 0, stream>>>(h, rowptr, colsrc, wcsr, dinv, agg, N);
    mm_kernel<64><<<nbN, 256, 0, stream>>>(agg, W4, b4, h, N);

    pool_kernel<<<256, 256, 0, stream>>>(h, pooled, N);
    out_kernel<<<1, 64, 0, stream>>>(pooled, Wr, br, out);
}